// Round 15
// baseline (306.262 us; speedup 1.0000x reference)
//
#include <hip/hip_runtime.h>
#include <math.h>

// B=16, DIM=64, RANK=32, H=W=128, E=4, K=2, BINS=8, FREQ_DIM=64, KS=7
// Round 15: (1) twiddle table in global memory (k_transW) -- removes 13 sincosf
// per thread in both FFT kernels; (2) k_combine 2-pass epilogue: obuf reuses
// dead xs/bs2 LDS, out written as 128B float4 segments with shortcut folded.

namespace {

struct cpx { float x, y; };
struct TwB {
  cpx t0;        // stage-0 twiddle (in-lane butterfly)
  cpx ws[6];     // per-stage twiddle, = (1,0) on lower lanes
  float sg[6];   // per-stage sign: +1 lower, -1 upper
};

using bf16x8 = __attribute__((ext_vector_type(8))) short;
using f32x4  = __attribute__((ext_vector_type(4))) float;

__device__ __forceinline__ short f2bf(float f){
  unsigned u = __float_as_uint(f);
  u += 0x7FFF + ((u >> 16) & 1);           // RNE
  return (short)(u >> 16);
}

__device__ __forceinline__ cpx cmul(cpx a, cpx b){ return {a.x*b.x - a.y*b.y, a.x*b.y + a.y*b.x}; }

__device__ __forceinline__ void init_twb(TwB &T, int lane, const float2* __restrict__ tw128){
  float2 v0 = tw128[lane];
  T.t0 = {v0.x, v0.y};
  int m = 32;
  #pragma unroll
  for (int s = 0; s < 6; s++){
    bool up = (lane & m) != 0;
    float2 wv = tw128[(lane & (m-1)) * (64/m)];
    T.ws[s] = up ? cpx{wv.x, wv.y} : cpx{1.0f, 0.0f};
    T.sg[s] = up ? -1.0f : 1.0f;
    m >>= 1;
  }
}

__device__ __forceinline__ int br6(int l){ return (int)(__brev((unsigned)l) >> 26); }
__device__ __forceinline__ int pos7(int j){ return ((j & 1) << 6) | (j >> 1); }

// 128-pt DIF FFT across one wave: lane holds a=in[l], b=in[l+64].
// Output: a = F[2*br6(l)], b = F[2*br6(l)+1]. Branchless.
__device__ __forceinline__ void fft128(cpx &a, cpx &b, int lane, const TwB &T){
  cpx u{a.x + b.x, a.y + b.y};
  cpx v{a.x - b.x, a.y - b.y};
  v = cmul(v, T.t0);
  a = u; b = v;
  int m = 32;
  #pragma unroll
  for (int s = 0; s < 6; s++){
    float pax = __shfl_xor(a.x, m);
    float pay = __shfl_xor(a.y, m);
    float pbx = __shfl_xor(b.x, m);
    float pby = __shfl_xor(b.y, m);
    float sg = T.sg[s];
    cpx w = T.ws[s];
    cpx ta{fmaf(sg, a.x, pax), fmaf(sg, a.y, pay)};
    cpx tb{fmaf(sg, b.x, pbx), fmaf(sg, b.y, pby)};
    a = cmul(ta, w);
    b = cmul(tb, w);
    m >>= 1;
  }
}

__device__ __forceinline__ float gelu_exact(float v){
  return 0.5f * v * (1.0f + erff(v * 0.70710678118654752f));
}

__device__ __forceinline__ float silu(float v){
  return v / (1.0f + expf(-v));
}

// ---------------- kernels ----------------

// transposes proj0 + builds the 128-pt twiddle table W128^k = exp(-2pi i k/128)
__global__ __launch_bounds__(256) void k_transW(const float* __restrict__ proj0, float* __restrict__ p0t,
                                                float2* __restrict__ tw128){
  int t = threadIdx.x;
  if (t < 128){
    float s, c;
    sincosf(-6.283185307179586f * (float)t * (1.0f/128.0f), &s, &c);
    tw128[t] = make_float2(c, s);
  }
  for (int idx = t; idx < 2048; idx += 256){
    int r = idx >> 6, c = idx & 63;
    p0t[0*2048 + c*32 + r] = proj0[0*2048 + idx];
    p0t[1*2048 + c*32 + r] = proj0[2*2048 + idx];
  }
}

// Fused 2-D rFFT per (b,c) + radial energy partials + xmean. 512 threads.
__global__ __launch_bounds__(512) void k_fft2fwd(const float* __restrict__ x, float2* __restrict__ X,
                                                 float* __restrict__ part_w, float* __restrict__ xmean,
                                                 const float2* __restrict__ tw128){
  __shared__ float2 z[8192];
  int bc = blockIdx.x; int t = threadIdx.x;
  int lane = t & 63, wv = t >> 6;
  TwB T; init_twb(T, lane, tw128);
  const float* img = x + (size_t)bc * 16384;
  int rb = br6(lane);

  // row FFTs, two real rows packed per complex FFT: pair p -> rows 2p, 2p+1
  #pragma unroll 4
  for (int k = 0; k < 8; k++){
    int p = wv*8 + k;
    int h0 = 2*p, h1 = 2*p + 1;
    cpx a{img[h0*128 + lane],      img[h1*128 + lane]};
    cpx b{img[h0*128 + lane + 64], img[h1*128 + lane + 64]};
    fft128(a, b, lane, T);
    int ia = (p << 7) | (rb ^ p);
    z[ia]      = make_float2(a.x, a.y);
    z[ia | 64] = make_float2(b.x, b.y);
  }
  __syncthreads();

  // column FFTs: unpack two-rows trick on read; results staged in registers.
  float rax[8], ray[8], rbx[8], rby[8];
  #pragma unroll
  for (int k = 0; k < 8; k++){
    int jj = wv*8 + k;
    int p  = lane >> 1, s = lane & 1;
    int p2 = 32 + p;
    cpx a, b;
    if (jj == 0){
      float2 z0  = z[(p << 7)  | (0  ^ p)];
      float2 z64 = z[(p << 7)  | (32 ^ p)];
      float2 w0  = z[(p2 << 7) | (0  ^ p2)];
      float2 w64 = z[(p2 << 7) | (32 ^ p2)];
      a = { s ? z0.y : z0.x, s ? z64.y : z64.x };
      b = { s ? w0.y : w0.x, s ? w64.y : w64.x };
    } else {
      int jm = 128 - jj;
      int pj = pos7(jj), pm = pos7(jm);
      float2 z1 = z[(p << 7) | (pj ^ p)],  z2 = z[(p << 7) | (pm ^ p)];
      if (s == 0) a = { 0.5f*(z1.x + z2.x), 0.5f*(z1.y - z2.y) };
      else        a = { 0.5f*(z1.y + z2.y), 0.5f*(z2.x - z1.x) };
      float2 w1 = z[(p2 << 7) | (pj ^ p2)], w2 = z[(p2 << 7) | (pm ^ p2)];
      if (s == 0) b = { 0.5f*(w1.x + w2.x), 0.5f*(w1.y - w2.y) };
      else        b = { 0.5f*(w1.y + w2.y), 0.5f*(w2.x - w1.x) };
    }
    fft128(a, b, lane, T);
    rax[k] = a.x; ray[k] = a.y; rbx[k] = b.x; rby[k] = b.y;
  }
  __syncthreads();
  #pragma unroll
  for (int k = 0; k < 8; k++){
    int jj = wv*8 + k;
    int ia = (jj << 7) | (rb ^ jj);
    z[ia]      = make_float2(rax[k], ray[k]);
    z[ia | 64] = make_float2(rbx[k], rby[k]);
  }
  __syncthreads();

  if (t == 0) xmean[bc] = z[0].x * (1.0f/16384.0f);

  // radial energy
  float edges[9];
  float step = sqrtf(8192.0f) * 0.125f;
  #pragma unroll
  for (int k = 0; k <= 8; k++) edges[k] = step * (float)k;
  float acc[8] = {0,0,0,0,0,0,0,0};
  for (int idx = t; idx < 64*128; idx += 512){
    int j = idx >> 7, i = idx & 127;
    if (j == 0){
      float2 c0 = z[pos7(i)];
      int in_ = (128 - i) & 127;
      float2 d0v = z[pos7(in_)];
      float x0r = 0.5f*(c0.x + d0v.x), x0i = 0.5f*(c0.y - d0v.y);
      float x6r = 0.5f*(c0.y + d0v.y), x6i = 0.5f*(d0v.x - c0.x);
      float m0 = sqrtf(x0r*x0r + x0i*x0i) * (1.0f/16384.0f);
      float m6 = sqrtf(x6r*x6r + x6i*x6i) * (1.0f/16384.0f);
      float dyv = (float)(i - 64);
      float d0 = sqrtf(dyv*dyv + 4096.0f);
      float d6 = fabsf(dyv);
      #pragma unroll
      for (int k = 0; k < 8; k++){
        if (d0 >= edges[k] && d0 < edges[k+1]) acc[k] += m0;
        if (d6 >= edges[k] && d6 < edges[k+1]) acc[k] += m6;
      }
    } else {
      float2 zv = z[(j << 7) | (pos7(i) ^ j)];
      float mag = sqrtf(zv.x*zv.x + zv.y*zv.y) * (2.0f/16384.0f);
      float dy = (float)(i - 64), dx = (float)(j - 64);
      float d = sqrtf(dy*dy + dx*dx);
      #pragma unroll
      for (int k = 0; k < 8; k++)
        if (d >= edges[k] && d < edges[k+1]) acc[k] += mag;
    }
  }
  #pragma unroll
  for (int k = 0; k < 8; k++){
    float v = acc[k];
    for (int off = 32; off > 0; off >>= 1) v += __shfl_xor(v, off);
    if (lane == 0) part_w[(bc*8 + wv)*8 + k] = v;
  }

  // coalesced X write-out
  float2* Xo = X + (size_t)bc * (65*128);
  for (int idx = t; idx < 65*128; idx += 512){
    int j = idx >> 7, i = idx & 127;
    float2 v;
    if (j == 0){
      float2 c0 = z[pos7(i)];
      int in_ = (128 - i) & 127;
      float2 d0v = z[pos7(in_)];
      v = make_float2(0.5f*(c0.x + d0v.x), 0.5f*(c0.y - d0v.y));
    } else if (j == 64){
      float2 c0 = z[pos7(i)];
      int in_ = (128 - i) & 127;
      float2 d0v = z[pos7(in_)];
      v = make_float2(0.5f*(c0.y + d0v.y), 0.5f*(d0v.x - c0.x));
    } else {
      v = z[(j << 7) | (pos7(i) ^ j)];
    }
    Xo[idx] = v;
  }
}

__global__ __launch_bounds__(128) void k_routing(const float* __restrict__ xmean, const float* __restrict__ part_w,
    const float* __restrict__ noise, const float* __restrict__ gate_w,
    const float* __restrict__ fg_w1, const float* __restrict__ fg_b1, const float* __restrict__ fg_w2,
    int* __restrict__ slot_e, int* __restrict__ slot_of, float* __restrict__ slot_g){
  __shared__ float femb[16][8];
  __shared__ float hid[16][64];
  __shared__ float lgt[16][4];
  int t = threadIdx.x;
  {
    int b = t >> 3, k = t & 7;
    float s = 0.f;
    for (int c = 0; c < 64; c++)
      for (int w = 0; w < 8; w++)
        s += part_w[((b*64 + c)*8 + w)*8 + k];
    femb[b][k] = s * (1.0f/64.0f);
  }
  __syncthreads();
  for (int idx = t; idx < 16*64; idx += 128){
    int b = idx >> 6, f = idx & 63;
    float s = fg_b1[f];
    for (int k = 0; k < 8; k++) s += femb[b][k] * fg_w1[f*8 + k];
    hid[b][f] = fmaxf(s, 0.f);
  }
  __syncthreads();
  if (t < 64){
    int b = t >> 2, e = t & 3;
    float s = 0.f;
    for (int c = 0; c < 64; c++) s += xmean[b*64 + c] * gate_w[e*64 + c];
    for (int f = 0; f < 64; f++) s += hid[b][f] * fg_w2[e*64 + f];
    lgt[b][e] = s + noise[b*4 + e] * 0.25f;   // NOISE_STD = 1/E
  }
  __syncthreads();
  if (t < 16){
    int b = t;
    float m = fmaxf(fmaxf(lgt[b][0], lgt[b][1]), fmaxf(lgt[b][2], lgt[b][3]));
    float p[4]; float sum = 0.f;
    for (int e = 0; e < 4; e++){ p[e] = expf(lgt[b][e] - m); sum += p[e]; }
    for (int e = 0; e < 4; e++) p[e] /= sum;
    int i1 = 0;
    for (int e = 1; e < 4; e++) if (p[e] > p[i1]) i1 = e;   // ties -> lowest idx (lax.top_k)
    int i2 = -1;
    for (int e = 0; e < 4; e++){ if (e == i1) continue; if (i2 < 0 || p[e] > p[i2]) i2 = e; }
    slot_e[b*2 + 0] = i1;
    slot_e[b*2 + 1] = i2;
    slot_g[b*2 + 0] = p[i1];
    slot_g[b*2 + 1] = p[i2];
    for (int e = 0; e < 4; e++) slot_of[b*4 + e] = (e == i1) ? 0 : ((e == i2) ? 1 : -1);
  }
}

// Both freq experts in one pass over X; weights via contiguous wave-uniform s_loads.
__global__ __launch_bounds__(256) void k_projfreq(const float2* __restrict__ X, const float* __restrict__ p0t,
    float2* __restrict__ Y, const int* __restrict__ slot_e,
    const float* __restrict__ hg_gain, const float* __restrict__ hg_decay,
    const float* __restrict__ lg_gain, const float* __restrict__ lg_decay){
  int b = blockIdx.z;
  int e0 = __builtin_amdgcn_readfirstlane(slot_e[b*2 + 0]);
  int e1 = __builtin_amdgcn_readfirstlane(slot_e[b*2 + 1]);
  bool f0 = (e0 == 0) || (e0 == 2);
  bool f1 = (e1 == 0) || (e1 == 2);
  if (!f0 && !f1) return;
  int j = blockIdx.y;
  int i0 = blockIdx.x * 64;
  int t = threadIdx.x;
  int lane = t & 63;
  int w = __builtin_amdgcn_readfirstlane(t >> 6);
  __shared__ float2 sx[64][64];
  for (int idx = t; idx < 4096; idx += 256){
    int c = idx >> 6, ii = idx & 63;
    sx[c][ii] = X[(((size_t)(b*64 + c))*65 + j)*128 + i0 + ii];
  }
  __syncthreads();
  int i = i0 + lane;
  const float* W0 = p0t + ((f0 ? (e0 >> 1) : (e1 >> 1)) * 2048) + w*8;
  const float* W1 = p0t + ((f1 ? (e1 >> 1) : (e0 >> 1)) * 2048) + w*8;
  float a0x[8] = {0,0,0,0,0,0,0,0}, a0y[8] = {0,0,0,0,0,0,0,0};
  float a1x[8] = {0,0,0,0,0,0,0,0}, a1y[8] = {0,0,0,0,0,0,0,0};
  for (int c = 0; c < 64; c++){
    float2 xv = sx[c][lane];
    const float* wc0 = W0 + c*32;
    const float* wc1 = W1 + c*32;
    #pragma unroll
    for (int k = 0; k < 8; k++){
      float w0v = wc0[k];
      a0x[k] += w0v * xv.x; a0y[k] += w0v * xv.y;
      float w1v = wc1[k];
      a1x[k] += w1v * xv.x; a1y[k] += w1v * xv.y;
    }
  }
  float fy = (float)(i < 64 ? i : i - 128) * (1.0f/128.0f);
  float fx = (float)j * (1.0f/128.0f);
  float fg = sqrtf(fy*fy + fx*fx);
  if (f0){
    float gain, decay, cmax;
    if (e0 == 0){ gain = *hg_gain; decay = *hg_decay; cmax = 3.0f; }
    else        { gain = *lg_gain; decay = *lg_decay; cmax = 1.0f; }
    float filt = (1.0f - expf(-gain*fg)) * expf(-decay*fg);
    filt = fminf(fmaxf(filt, 0.0f), cmax) * (1.0f/16384.0f);
    int bs = b*2 + 0;
    #pragma unroll
    for (int k = 0; k < 8; k++){
      int r = w*8 + k;
      Y[((size_t)(bs*32 + r))*8320 + j*128 + i] = make_float2(a0x[k]*filt, a0y[k]*filt);
    }
  }
  if (f1){
    float gain, decay, cmax;
    if (e1 == 0){ gain = *hg_gain; decay = *hg_decay; cmax = 3.0f; }
    else        { gain = *lg_gain; decay = *lg_decay; cmax = 1.0f; }
    float filt = (1.0f - expf(-gain*fg)) * expf(-decay*fg);
    filt = fminf(fmaxf(filt, 0.0f), cmax) * (1.0f/16384.0f);
    int bs = b*2 + 1;
    #pragma unroll
    for (int k = 0; k < 8; k++){
      int r = w*8 + k;
      Y[((size_t)(bs*32 + r))*8320 + j*128 + i] = make_float2(a1x[k]*filt, a1y[k]*filt);
    }
  }
}

// Fused inverse 2-D FFT per (bs,r) for freq slots; body written IN PLACE. 512 threads.
__global__ __launch_bounds__(512) void k_ifft2(float2* __restrict__ Y, const int* __restrict__ slot_e,
                                               const float2* __restrict__ tw128){
  int blk = blockIdx.x;
  int bs = blk >> 5, r = blk & 31;
  int es = slot_e[bs];
  if (es == 1 || es == 3) return;     // conv slots skip
  __shared__ float2 z[8192];
  int t = threadIdx.x; int lane = t & 63, wv = t >> 6;
  TwB T; init_twb(T, lane, tw128);
  int rb = br6(lane);
  float2* Yb = Y + (size_t)(bs*32 + r) * 8320;

  // load; row 0 packed: P[i] = Y[0][i] + i*Y[64][i]
  for (int idx = t; idx < 8192; idx += 512){
    int j = idx >> 7, i = idx & 127;
    if (j == 0){
      float2 y0 = Yb[i];
      float2 y6 = Yb[8192 + i];
      z[pos7(i)] = make_float2(y0.x - y6.y, y0.y + y6.x);
    } else {
      z[(j << 7) | (pos7(i) ^ j)] = Yb[idx];
    }
  }
  __syncthreads();

  // inverse column FFTs (unnormalized), in place per column
  #pragma unroll
  for (int k = 0; k < 8; k++){
    int jj = wv*8 + k;
    float2 z0 = z[(jj << 7) | (pos7(lane) ^ jj)];
    float2 z1 = z[(jj << 7) | ((pos7(lane) + 32) ^ jj)];
    cpx a{z0.x, -z0.y}, b{z1.x, -z1.y};
    fft128(a, b, lane, T);
    int ia = (jj << 7) | (rb ^ jj);
    z[ia]      = make_float2(a.x, -a.y);
    z[ia | 64] = make_float2(b.x, -b.y);
  }
  __syncthreads();

  // inverse row transform: two real output rows per complex inverse FFT
  float* body = (float*)Yb;
  #pragma unroll 2
  for (int k = 0; k < 8; k++){
    int p = wv*8 + k;
    int h = 2*p, h1 = 2*p + 1;
    int ph = pos7(h), ph1 = pos7(h1);
    cpx a, b;
    if (lane == 0){
      float2 c0 = z[ph], c1 = z[ph1];
      a = { c0.x, c1.x };
      b = { c0.y, c1.y };
    } else {
      float2 yh = z[(lane << 7) | (ph ^ lane)];
      float2 y1 = z[(lane << 7) | (ph1 ^ lane)];
      a = { yh.x - y1.y, yh.y + y1.x };
      int lm = 64 - lane;
      float2 zh  = z[(lm << 7) | (ph ^ lm)];
      float2 z1_ = z[(lm << 7) | (ph1 ^ lm)];
      b = { zh.x + z1_.y, z1_.x - zh.y };
    }
    a.y = -a.y; b.y = -b.y;        // conj
    fft128(a, b, lane, T);
    int n0 = 2*rb;
    body[h*128 + n0]      = a.x;
    body[h1*128 + n0]     = -a.y;
    body[h*128 + n0 + 1]  = b.x;
    body[h1*128 + n0 + 1] = -b.y;
  }
}

// A[bs][r] = P0[e_s] x[b] for conv slots, on MFMA with bf16 LDS staging.
__global__ __launch_bounds__(256) void k_projA(const float* __restrict__ x, const float* __restrict__ proj0,
    const int* __restrict__ slot_e, float* __restrict__ A){
  int b = blockIdx.y;
  int e0 = __builtin_amdgcn_readfirstlane(slot_e[b*2 + 0]);
  int e1 = __builtin_amdgcn_readfirstlane(slot_e[b*2 + 1]);
  bool c0 = (e0 == 1) || (e0 == 3);
  bool c1 = (e1 == 1) || (e1 == 3);
  if (!c0 && !c1) return;
  __shared__ unsigned short xs[128][72];
  int px0 = blockIdx.x * 128;
  int t = threadIdx.x;
  int w = t >> 6, lane = t & 63;
  int h = lane & 15, g = lane >> 4;
  const float* xb = x + (size_t)b*64*16384;

  for (int idx = t; idx < 2048; idx += 256){
    int c = idx >> 5, pq = idx & 31;
    float4 v = *(const float4*)&xb[(size_t)c*16384 + px0 + pq*4];
    xs[pq*4 + 0][c] = (unsigned short)f2bf(v.x);
    xs[pq*4 + 1][c] = (unsigned short)f2bf(v.y);
    xs[pq*4 + 2][c] = (unsigned short)f2bf(v.z);
    xs[pq*4 + 3][c] = (unsigned short)f2bf(v.w);
  }

  bf16x8 af[2][2][2];
  #pragma unroll
  for (int s = 0; s < 2; s++){
    bool cv = (s == 0) ? c0 : c1;
    if (!cv) continue;
    int e = (s == 0) ? e0 : e1;
    const float* P0 = proj0 + e*2048;
    #pragma unroll
    for (int mr = 0; mr < 2; mr++)
      #pragma unroll
      for (int k0 = 0; k0 < 2; k0++){
        const float* p = P0 + (mr*16 + h)*64 + k0*32 + g*8;
        bf16x8 v;
        #pragma unroll
        for (int j = 0; j < 8; j++) v[j] = f2bf(p[j]);
        af[s][mr][k0] = v;
      }
  }
  __syncthreads();

  int pxw = w*32;
  #pragma unroll
  for (int nt = 0; nt < 2; nt++){
    int pxl = pxw + nt*16;
    int px  = px0 + pxl;
    bf16x8 bx[2];
    #pragma unroll
    for (int k0 = 0; k0 < 2; k0++)
      bx[k0] = *(bf16x8*)&xs[pxl + h][k0*32 + g*8];
    #pragma unroll
    for (int s = 0; s < 2; s++){
      bool cv = (s == 0) ? c0 : c1;
      if (!cv) continue;
      float* Ab = A + (size_t)((b*2 + s)*32)*16384;
      #pragma unroll
      for (int mr = 0; mr < 2; mr++){
        f32x4 acc = {0.f, 0.f, 0.f, 0.f};
        acc = __builtin_amdgcn_mfma_f32_16x16x32_bf16(af[s][mr][0], bx[0], acc, 0, 0, 0);
        acc = __builtin_amdgcn_mfma_f32_16x16x32_bf16(af[s][mr][1], bx[1], acc, 0, 0, 0);
        #pragma unroll
        for (int reg = 0; reg < 4; reg++){
          int r = mr*16 + g*4 + reg;
          Ab[(size_t)r*16384 + px + h] = acc[reg];
        }
      }
    }
  }
}

// Expert 1 fused: dw3 -> gelu -> dw3, LDS-tiled (16 out rows x 128)
__global__ __launch_bounds__(256) void k_conv3(const float* __restrict__ A, float* __restrict__ bodyY,
    const float* __restrict__ w1g, const float* __restrict__ b1g,
    const float* __restrict__ w2g, const float* __restrict__ b2g,
    const int* __restrict__ slot_of){
  int by = blockIdx.y; int b = by >> 5, r = by & 31;
  int slot = slot_of[b*4 + 1];
  if (slot < 0) return;
  int bs = b*2 + slot;
  int h0 = blockIdx.x * 16;
  int t = threadIdx.x;
  __shared__ float sin_[20*130];
  __shared__ float st[18*130];
  for (int i = t; i < 20*130; i += 256) sin_[i] = 0.f;
  for (int i = t; i < 18*130; i += 256) st[i] = 0.f;
  float w1[9], w2[9];
  #pragma unroll
  for (int k = 0; k < 9; k++){ w1[k] = w1g[r*9 + k]; w2[k] = w2g[r*9 + k]; }
  float b1 = b1g[r], b2 = b2g[r];
  __syncthreads();
  const float* ip = A + (size_t)(bs*32 + r)*16384;
  for (int idx = t; idx < 20*128; idx += 256){
    int li = idx >> 7, ww = idx & 127;
    int ih = h0 - 2 + li;
    if (ih >= 0 && ih < 128) sin_[li*130 + 1 + ww] = ip[ih*128 + ww];
  }
  __syncthreads();
  for (int idx = t; idx < 18*128; idx += 256){
    int li = idx >> 7, ww = idx & 127;
    int hs = h0 - 1 + li;
    if (hs >= 0 && hs < 128){
      float acc = b1;
      #pragma unroll
      for (int kh = 0; kh < 3; kh++)
        #pragma unroll
        for (int kw = 0; kw < 3; kw++)
          acc += w1[kh*3 + kw] * sin_[(li + kh)*130 + ww + kw];
      st[li*130 + 1 + ww] = gelu_exact(acc);
    }
  }
  __syncthreads();
  float* op = bodyY + (size_t)(bs*32 + r)*16640;
  for (int idx = t; idx < 16*128; idx += 256){
    int li = idx >> 7, ww = idx & 127;
    int ho = h0 + li;
    float acc = b2;
    #pragma unroll
    for (int kh = 0; kh < 3; kh++)
      #pragma unroll
      for (int kw = 0; kw < 3; kw++)
        acc += w2[kh*3 + kw] * st[(li + kh)*130 + ww + kw];
    op[ho*128 + ww] = acc;
  }
}

// Expert 3 fused: dw7 -> gelu -> avgpool3 (count_include_pad)
__global__ __launch_bounds__(256) void k_conv7(const float* __restrict__ A, float* __restrict__ bodyY,
    const float* __restrict__ wg, const float* __restrict__ bg,
    const int* __restrict__ slot_of){
  int by = blockIdx.y; int b = by >> 5, r = by & 31;
  int slot = slot_of[b*4 + 3];
  if (slot < 0) return;
  int bs = b*2 + slot;
  int h0 = blockIdx.x * 16;
  int t = threadIdx.x;
  __shared__ float sin_[24*134];
  __shared__ float st[18*134];
  __shared__ float wsh[49];
  for (int i = t; i < 24*134; i += 256) sin_[i] = 0.f;
  for (int i = t; i < 18*134; i += 256) st[i] = 0.f;
  if (t < 49) wsh[t] = wg[r*49 + t];
  float bias = bg[r];
  __syncthreads();
  const float* ip = A + (size_t)(bs*32 + r)*16384;
  for (int idx = t; idx < 24*128; idx += 256){
    int li = idx >> 7, ww = idx & 127;
    int ih = h0 - 4 + li;
    if (ih >= 0 && ih < 128) sin_[li*134 + 3 + ww] = ip[ih*128 + ww];
  }
  __syncthreads();
  for (int idx = t; idx < 18*128; idx += 256){
    int li = idx >> 7, ww = idx & 127;
    int hs = h0 - 1 + li;
    if (hs >= 0 && hs < 128){
      float acc = bias;
      #pragma unroll
      for (int kh = 0; kh < 7; kh++)
        #pragma unroll
        for (int kw = 0; kw < 7; kw++)
          acc += wsh[kh*7 + kw] * sin_[(li + kh)*134 + ww + kw];
      st[li*134 + 1 + ww] = gelu_exact(acc);
    }
  }
  __syncthreads();
  float* op = bodyY + (size_t)(bs*32 + r)*16640;
  for (int idx = t; idx < 16*128; idx += 256){
    int li = idx >> 7, ww = idx & 127;
    int ho = h0 + li;
    float acc = 0.f;
    #pragma unroll
    for (int kh = 0; kh < 3; kh++)
      #pragma unroll
      for (int kw = 0; kw < 3; kw++)
        acc += st[(li + kh)*134 + ww + kw];
    op[ho*128 + ww] = acc * (1.0f/9.0f);
  }
}

// Final combine on MFMA, 2-pass: pass1 = phase1 + sblk (both nt); pass2 reuses
// dead xs/bs2 LDS as obuf and writes out as 128B float4 strips per wave.
__global__ __launch_bounds__(256) void k_combine(const float* __restrict__ x, const float* __restrict__ bodyY,
    const float* __restrict__ proj1, const float* __restrict__ proj2,
    const int* __restrict__ slot_e, const float* __restrict__ slot_g,
    float* __restrict__ out){
  __shared__ __align__(16) unsigned char smem[57344];
  unsigned short (*xs)[72]            = (unsigned short(*)[72])(smem);            // [128][72]  18432 B
  unsigned short (*bs2)[128][36]      = (unsigned short(*)[128][36])(smem + 18432); // [2][128][36] 18432 B
  unsigned short (*sblk)[4][2][16][40] = (unsigned short(*)[4][2][16][40])(smem + 36864); // [2nt][4][2][16][40] 20480 B
  float* obuf = (float*)smem;          // [4][64][36] f32 = 36864 B (aliases xs+bs2 after sync)

  int b = blockIdx.y;
  int px0 = blockIdx.x * 128;
  int t = threadIdx.x;
  int w = t >> 6, lane = t & 63;
  int h = lane & 15, g = lane >> 4;
  int ea = __builtin_amdgcn_readfirstlane(slot_e[b*2 + 0]);
  int eb = __builtin_amdgcn_readfirstlane(slot_e[b*2 + 1]);
  float ga = slot_g[b*2 + 0], gb = slot_g[b*2 + 1];
  float gs = ga + gb;

  const float* xb = x + (size_t)b*64*16384;
  float* ob = out + (size_t)b*64*16384;
  const float* Bd0 = bodyY + (size_t)(b*2 + 0)*32*16640;
  const float* Bd1 = bodyY + (size_t)(b*2 + 1)*32*16640;

  // stage x tile: 64 c x 128 px, float4 coalesced -> bf16 transposed
  for (int idx = t; idx < 2048; idx += 256){
    int c = idx >> 5, pq = idx & 31;
    float4 v = *(const float4*)&xb[(size_t)c*16384 + px0 + pq*4];
    xs[pq*4 + 0][c] = (unsigned short)f2bf(v.x);
    xs[pq*4 + 1][c] = (unsigned short)f2bf(v.y);
    xs[pq*4 + 2][c] = (unsigned short)f2bf(v.z);
    xs[pq*4 + 3][c] = (unsigned short)f2bf(v.w);
  }
  // stage body tiles: 2 slots x 32 r x 128 px
  for (int idx = t; idx < 2048; idx += 256){
    int s = idx >> 10, r = (idx >> 5) & 31, pq = idx & 31;
    const float* Bod = (s == 0) ? Bd0 : Bd1;
    float4 v = *(const float4*)&Bod[(size_t)r*16640 + px0 + pq*4];
    bs2[s][pq*4 + 0][r] = (unsigned short)f2bf(v.x);
    bs2[s][pq*4 + 1][r] = (unsigned short)f2bf(v.y);
    bs2[s][pq*4 + 2][r] = (unsigned short)f2bf(v.z);
    bs2[s][pq*4 + 3][r] = (unsigned short)f2bf(v.w);
  }

  // A fragments phase1: P1[r][c] natural; a1[slot][mr][k0]
  bf16x8 a1[2][2][2];
  #pragma unroll
  for (int s = 0; s < 2; s++){
    const float* P1 = proj1 + (s == 0 ? ea : eb)*2048;
    #pragma unroll
    for (int mr = 0; mr < 2; mr++)
      #pragma unroll
      for (int k0 = 0; k0 < 2; k0++){
        const float* p = P1 + (mr*16 + h)*64 + k0*32 + g*8;
        bf16x8 v;
        #pragma unroll
        for (int j = 0; j < 8; j++) v[j] = f2bf(p[j]);
        a1[s][mr][k0] = v;
      }
  }
  // A fragments phase2: P2[c][r] natural; a2[slot][mc]
  bf16x8 a2[2][4];
  #pragma unroll
  for (int s = 0; s < 2; s++){
    const float* P2 = proj2 + (s == 0 ? ea : eb)*2048;
    #pragma unroll
    for (int mc = 0; mc < 4; mc++){
      const float* p = P2 + (mc*16 + h)*32 + g*8;
      bf16x8 v;
      #pragma unroll
      for (int j = 0; j < 8; j++) v[j] = f2bf(p[j]);
      a2[s][mc] = v;
    }
  }
  __syncthreads();

  int pxw = w*32;
  // pass 1: phase-1 MFMA + s-values into sblk, both nt
  #pragma unroll
  for (int nt = 0; nt < 2; nt++){
    int pxl = pxw + nt*16;
    bf16x8 bx[2];
    #pragma unroll
    for (int k0 = 0; k0 < 2; k0++)
      bx[k0] = *(bf16x8*)&xs[pxl + h][k0*32 + g*8];
    f32x4 acc1[2][2];
    #pragma unroll
    for (int s = 0; s < 2; s++)
      #pragma unroll
      for (int mr = 0; mr < 2; mr++){
        f32x4 acc = {0.f, 0.f, 0.f, 0.f};
        acc = __builtin_amdgcn_mfma_f32_16x16x32_bf16(a1[s][mr][0], bx[0], acc, 0, 0, 0);
        acc = __builtin_amdgcn_mfma_f32_16x16x32_bf16(a1[s][mr][1], bx[1], acc, 0, 0, 0);
        acc1[s][mr] = acc;
      }
    #pragma unroll
    for (int s = 0; s < 2; s++){
      float gw = (s == 0) ? ga : gb;
      #pragma unroll
      for (int mr = 0; mr < 2; mr++){
        int r0 = mr*16 + g*4;
        unsigned short b4[4];
        *(uint2*)b4 = *(uint2*)&bs2[s][pxl + h][r0];
        unsigned pk0, pk1;
        {
          float bv0 = __uint_as_float(((unsigned)b4[0]) << 16);
          float bv1 = __uint_as_float(((unsigned)b4[1]) << 16);
          float bv2 = __uint_as_float(((unsigned)b4[2]) << 16);
          float bv3 = __uint_as_float(((unsigned)b4[3]) << 16);
          float s0 = gw * bv0 * silu(acc1[s][mr][0]);
          float s1 = gw * bv1 * silu(acc1[s][mr][1]);
          float s2 = gw * bv2 * silu(acc1[s][mr][2]);
          float s3 = gw * bv3 * silu(acc1[s][mr][3]);
          pk0 = (unsigned)(unsigned short)f2bf(s0) | ((unsigned)(unsigned short)f2bf(s1) << 16);
          pk1 = (unsigned)(unsigned short)f2bf(s2) | ((unsigned)(unsigned short)f2bf(s3) << 16);
        }
        uint2 pv; pv.x = pk0; pv.y = pk1;
        *(uint2*)&sblk[nt][w][s][h][r0] = pv;
      }
    }
  }
  __syncthreads();   // xs/bs2 dead everywhere; obuf aliases them from here

  // pass 2: phase-2 MFMA -> obuf (wave-private slice)
  #pragma unroll
  for (int nt = 0; nt < 2; nt++){
    bf16x8 sb0 = *(bf16x8*)&sblk[nt][w][0][h][g*8];
    bf16x8 sb1 = *(bf16x8*)&sblk[nt][w][1][h][g*8];
    #pragma unroll
    for (int mc = 0; mc < 4; mc++){
      f32x4 acc = {0.f, 0.f, 0.f, 0.f};
      acc = __builtin_amdgcn_mfma_f32_16x16x32_bf16(a2[0][mc], sb0, acc, 0, 0, 0);
      acc = __builtin_amdgcn_mfma_f32_16x16x32_bf16(a2[1][mc], sb1, acc, 0, 0, 0);
      #pragma unroll
      for (int reg = 0; reg < 4; reg++){
        int c = mc*16 + g*4 + reg;
        obuf[(w*64 + c)*36 + nt*16 + h] = acc[reg];
      }
    }
  }
  // epilogue: wave-private 32-px strips, float4 coalesced (128B segments)
  int fq = lane & 7, cr = lane >> 3;
  const float* xw = xb + px0 + w*32;
  float* ow = ob + px0 + w*32;
  #pragma unroll
  for (int i = 0; i < 8; i++){
    int c = i*8 + cr;
    float4 v = *(float4*)&obuf[(w*64 + c)*36 + fq*4];
    float4 xv4 = *(const float4*)&xw[(size_t)c*16384 + fq*4];
    *(float4*)&ow[(size_t)c*16384 + fq*4] =
      make_float4(gs*xv4.x + v.x, gs*xv4.y + v.y, gs*xv4.z + v.z, gs*xv4.w + v.w);
  }
}

} // namespace

extern "C" void kernel_launch(void* const* d_in, const int* in_sizes, int n_in,
                              void* d_out, int out_size, void* d_ws, size_t ws_size,
                              hipStream_t stream) {
  (void)in_sizes; (void)n_in; (void)out_size; (void)ws_size;
  const float* x        = (const float*)d_in[0];
  const float* noise    = (const float*)d_in[1];
  const float* gate_w   = (const float*)d_in[2];
  const float* fg_w1    = (const float*)d_in[3];
  const float* fg_b1    = (const float*)d_in[4];
  const float* fg_w2    = (const float*)d_in[5];
  const float* proj0    = (const float*)d_in[6];
  const float* proj1    = (const float*)d_in[7];
  const float* proj2    = (const float*)d_in[8];
  const float* hg_gain  = (const float*)d_in[9];
  const float* hg_decay = (const float*)d_in[10];
  const float* hf_w1    = (const float*)d_in[11];
  const float* hf_b1    = (const float*)d_in[12];
  const float* hf_w2    = (const float*)d_in[13];
  const float* hf_b2    = (const float*)d_in[14];
  const float* lg_gain  = (const float*)d_in[15];
  const float* lg_decay = (const float*)d_in[16];
  const float* lf_w     = (const float*)d_in[17];
  const float* lf_b     = (const float*)d_in[18];
  float* out = (float*)d_out;

  // ws (floats):
  //  [0, 17039360)            X spectra [1024][65][128] f2 ; later overlaid by A [32 bs][32 r][16384]
  //  [17039360, 34078720)     Yspec/body [32 bs][32 r][65*128 f2]
  //  tail: xmean 1024 | part_w 65536 | p0t 4096 | tw128 256 | slot_g 32 | slot_e 32 (int) | slot_of 64 (int)
  float* ws = (float*)d_ws;
  float2* X  = (float2*)ws;
  float*  A  = ws;
  float*  Yf = ws + 17039360;
  float2* Y2 = (float2*)Yf;
  float*  tail   = ws + 34078720;
  float*  xmean  = tail;
  float*  part_w = xmean + 1024;
  float*  p0t    = part_w + 65536;
  float*  tw128f = p0t + 4096;
  float2* tw128  = (float2*)tw128f;
  float*  slot_g = tw128f + 256;
  int*    slot_e = (int*)(slot_g + 32);
  int*    slot_of = slot_e + 32;

  // weight transpose + twiddle table (must precede FFT kernels; stream-ordered)
  k_transW<<<1, 256, 0, stream>>>(proj0, p0t, tw128);
  k_fft2fwd<<<1024, 512, 0, stream>>>(x, X, part_w, xmean, tw128);
  k_routing<<<1, 128, 0, stream>>>(xmean, part_w, noise, gate_w, fg_w1, fg_b1, fg_w2,
                                   slot_e, slot_of, slot_g);

  // frequency-domain projections, both freq experts in one X pass
  k_projfreq<<<dim3(2,65,16), 256, 0, stream>>>(X, p0t, Y2, slot_e,
                                                hg_gain, hg_decay, lg_gain, lg_decay);

  // A for conv slots on MFMA (overlays X; X dead after projfreq)
  k_projA<<<dim3(128,16), 256, 0, stream>>>(x, proj0, slot_e, A);

  // inverse FFTs for freq slots (bodies in place in Yspec)
  k_ifft2<<<1024, 512, 0, stream>>>(Y2, slot_e, tw128);

  // conv experts (bodies into Yspec slots)
  k_conv3<<<dim3(8,512), 256, 0, stream>>>(A, Yf, hf_w1, hf_b1, hf_w2, hf_b2, slot_of);
  k_conv7<<<dim3(8,512), 256, 0, stream>>>(A, Yf, lf_w, lf_b, slot_of);

  // final combine on MFMA, 2-pass epilogue
  k_combine<<<dim3(128,16), 256, 0, stream>>>(x, Yf, proj1, proj2, slot_e, slot_g, out);
}

// Round 16
// 299.285 us; speedup vs baseline: 1.0233x; 1.0233x over previous
//
#include <hip/hip_runtime.h>
#include <math.h>

// B=16, DIM=64, RANK=32, H=W=128, E=4, K=2, BINS=8, FREQ_DIM=64, KS=7
// Round 16: launch count 9 -> 6. transW folded into fft2fwd (in-LDS twiddles)
// and routing (p0t). ifft2+projA merged (independent; overlay invariant kept
// because projfreq completes first). conv3+conv7 merged via blockIdx.z.

namespace {

struct cpx { float x, y; };
struct TwB {
  cpx t0;
  cpx ws[6];
  float sg[6];
};

using bf16x8 = __attribute__((ext_vector_type(8))) short;
using f32x4  = __attribute__((ext_vector_type(4))) float;

__device__ __forceinline__ short f2bf(float f){
  unsigned u = __float_as_uint(f);
  u += 0x7FFF + ((u >> 16) & 1);           // RNE
  return (short)(u >> 16);
}

__device__ __forceinline__ cpx cmul(cpx a, cpx b){ return {a.x*b.x - a.y*b.y, a.x*b.y + a.y*b.x}; }

__device__ __forceinline__ void init_twb(TwB &T, int lane, const float2* __restrict__ tw128){
  float2 v0 = tw128[lane];
  T.t0 = {v0.x, v0.y};
  int m = 32;
  #pragma unroll
  for (int s = 0; s < 6; s++){
    bool up = (lane & m) != 0;
    float2 wv = tw128[(lane & (m-1)) * (64/m)];
    T.ws[s] = up ? cpx{wv.x, wv.y} : cpx{1.0f, 0.0f};
    T.sg[s] = up ? -1.0f : 1.0f;
    m >>= 1;
  }
}

__device__ __forceinline__ int br6(int l){ return (int)(__brev((unsigned)l) >> 26); }
__device__ __forceinline__ int pos7(int j){ return ((j & 1) << 6) | (j >> 1); }

// 128-pt DIF FFT across one wave. Branchless.
__device__ __forceinline__ void fft128(cpx &a, cpx &b, int lane, const TwB &T){
  cpx u{a.x + b.x, a.y + b.y};
  cpx v{a.x - b.x, a.y - b.y};
  v = cmul(v, T.t0);
  a = u; b = v;
  int m = 32;
  #pragma unroll
  for (int s = 0; s < 6; s++){
    float pax = __shfl_xor(a.x, m);
    float pay = __shfl_xor(a.y, m);
    float pbx = __shfl_xor(b.x, m);
    float pby = __shfl_xor(b.y, m);
    float sg = T.sg[s];
    cpx w = T.ws[s];
    cpx ta{fmaf(sg, a.x, pax), fmaf(sg, a.y, pay)};
    cpx tb{fmaf(sg, b.x, pbx), fmaf(sg, b.y, pby)};
    a = cmul(ta, w);
    b = cmul(tb, w);
    m >>= 1;
  }
}

__device__ __forceinline__ float gelu_exact(float v){
  return 0.5f * v * (1.0f + erff(v * 0.70710678118654752f));
}

__device__ __forceinline__ float silu(float v){
  return v / (1.0f + expf(-v));
}

// ---------------- kernels ----------------

// Fused 2-D rFFT per (b,c) + radial energy partials + xmean. 512 threads.
// Twiddle table built in-LDS (z[0..127]) before use.
__global__ __launch_bounds__(512) void k_fft2fwd(const float* __restrict__ x, float2* __restrict__ X,
                                                 float* __restrict__ part_w, float* __restrict__ xmean){
  __shared__ float2 z[8192];
  int bc = blockIdx.x; int t = threadIdx.x;
  int lane = t & 63, wv = t >> 6;
  if (t < 128){
    float s, c;
    sincosf(-6.283185307179586f * (float)t * (1.0f/128.0f), &s, &c);
    z[t] = make_float2(c, s);
  }
  __syncthreads();
  TwB T; init_twb(T, lane, (const float2*)z);
  __syncthreads();
  const float* img = x + (size_t)bc * 16384;
  int rb = br6(lane);

  // row FFTs, two real rows packed per complex FFT
  #pragma unroll 4
  for (int k = 0; k < 8; k++){
    int p = wv*8 + k;
    int h0 = 2*p, h1 = 2*p + 1;
    cpx a{img[h0*128 + lane],      img[h1*128 + lane]};
    cpx b{img[h0*128 + lane + 64], img[h1*128 + lane + 64]};
    fft128(a, b, lane, T);
    int ia = (p << 7) | (rb ^ p);
    z[ia]      = make_float2(a.x, a.y);
    z[ia | 64] = make_float2(b.x, b.y);
  }
  __syncthreads();

  // column FFTs
  float rax[8], ray[8], rbx[8], rby[8];
  #pragma unroll
  for (int k = 0; k < 8; k++){
    int jj = wv*8 + k;
    int p  = lane >> 1, s = lane & 1;
    int p2 = 32 + p;
    cpx a, b;
    if (jj == 0){
      float2 z0  = z[(p << 7)  | (0  ^ p)];
      float2 z64 = z[(p << 7)  | (32 ^ p)];
      float2 w0  = z[(p2 << 7) | (0  ^ p2)];
      float2 w64 = z[(p2 << 7) | (32 ^ p2)];
      a = { s ? z0.y : z0.x, s ? z64.y : z64.x };
      b = { s ? w0.y : w0.x, s ? w64.y : w64.x };
    } else {
      int jm = 128 - jj;
      int pj = pos7(jj), pm = pos7(jm);
      float2 z1 = z[(p << 7) | (pj ^ p)],  z2 = z[(p << 7) | (pm ^ p)];
      if (s == 0) a = { 0.5f*(z1.x + z2.x), 0.5f*(z1.y - z2.y) };
      else        a = { 0.5f*(z1.y + z2.y), 0.5f*(z2.x - z1.x) };
      float2 w1 = z[(p2 << 7) | (pj ^ p2)], w2 = z[(p2 << 7) | (pm ^ p2)];
      if (s == 0) b = { 0.5f*(w1.x + w2.x), 0.5f*(w1.y - w2.y) };
      else        b = { 0.5f*(w1.y + w2.y), 0.5f*(w2.x - w1.x) };
    }
    fft128(a, b, lane, T);
    rax[k] = a.x; ray[k] = a.y; rbx[k] = b.x; rby[k] = b.y;
  }
  __syncthreads();
  #pragma unroll
  for (int k = 0; k < 8; k++){
    int jj = wv*8 + k;
    int ia = (jj << 7) | (rb ^ jj);
    z[ia]      = make_float2(rax[k], ray[k]);
    z[ia | 64] = make_float2(rbx[k], rby[k]);
  }
  __syncthreads();

  if (t == 0) xmean[bc] = z[0].x * (1.0f/16384.0f);

  // radial energy
  float edges[9];
  float step = sqrtf(8192.0f) * 0.125f;
  #pragma unroll
  for (int k = 0; k <= 8; k++) edges[k] = step * (float)k;
  float acc[8] = {0,0,0,0,0,0,0,0};
  for (int idx = t; idx < 64*128; idx += 512){
    int j = idx >> 7, i = idx & 127;
    if (j == 0){
      float2 c0 = z[pos7(i)];
      int in_ = (128 - i) & 127;
      float2 d0v = z[pos7(in_)];
      float x0r = 0.5f*(c0.x + d0v.x), x0i = 0.5f*(c0.y - d0v.y);
      float x6r = 0.5f*(c0.y + d0v.y), x6i = 0.5f*(d0v.x - c0.x);
      float m0 = sqrtf(x0r*x0r + x0i*x0i) * (1.0f/16384.0f);
      float m6 = sqrtf(x6r*x6r + x6i*x6i) * (1.0f/16384.0f);
      float dyv = (float)(i - 64);
      float d0 = sqrtf(dyv*dyv + 4096.0f);
      float d6 = fabsf(dyv);
      #pragma unroll
      for (int k = 0; k < 8; k++){
        if (d0 >= edges[k] && d0 < edges[k+1]) acc[k] += m0;
        if (d6 >= edges[k] && d6 < edges[k+1]) acc[k] += m6;
      }
    } else {
      float2 zv = z[(j << 7) | (pos7(i) ^ j)];
      float mag = sqrtf(zv.x*zv.x + zv.y*zv.y) * (2.0f/16384.0f);
      float dy = (float)(i - 64), dx = (float)(j - 64);
      float d = sqrtf(dy*dy + dx*dx);
      #pragma unroll
      for (int k = 0; k < 8; k++)
        if (d >= edges[k] && d < edges[k+1]) acc[k] += mag;
    }
  }
  #pragma unroll
  for (int k = 0; k < 8; k++){
    float v = acc[k];
    for (int off = 32; off > 0; off >>= 1) v += __shfl_xor(v, off);
    if (lane == 0) part_w[(bc*8 + wv)*8 + k] = v;
  }

  // coalesced X write-out
  float2* Xo = X + (size_t)bc * (65*128);
  for (int idx = t; idx < 65*128; idx += 512){
    int j = idx >> 7, i = idx & 127;
    float2 v;
    if (j == 0){
      float2 c0 = z[pos7(i)];
      int in_ = (128 - i) & 127;
      float2 d0v = z[pos7(in_)];
      v = make_float2(0.5f*(c0.x + d0v.x), 0.5f*(c0.y - d0v.y));
    } else if (j == 64){
      float2 c0 = z[pos7(i)];
      int in_ = (128 - i) & 127;
      float2 d0v = z[pos7(in_)];
      v = make_float2(0.5f*(c0.y + d0v.y), 0.5f*(d0v.x - c0.x));
    } else {
      v = z[(j << 7) | (pos7(i) ^ j)];
    }
    Xo[idx] = v;
  }
}

// routing + p0t transpose (freq-expert proj0 -> [s][c][r])
__global__ __launch_bounds__(128) void k_routing(const float* __restrict__ xmean, const float* __restrict__ part_w,
    const float* __restrict__ noise, const float* __restrict__ gate_w,
    const float* __restrict__ fg_w1, const float* __restrict__ fg_b1, const float* __restrict__ fg_w2,
    const float* __restrict__ proj0, float* __restrict__ p0t,
    int* __restrict__ slot_e, int* __restrict__ slot_of, float* __restrict__ slot_g){
  __shared__ float femb[16][8];
  __shared__ float hid[16][64];
  __shared__ float lgt[16][4];
  int t = threadIdx.x;
  for (int idx = t; idx < 2048; idx += 128){
    int r = idx >> 6, c = idx & 63;
    p0t[0*2048 + c*32 + r] = proj0[0*2048 + idx];
    p0t[1*2048 + c*32 + r] = proj0[2*2048 + idx];
  }
  {
    int b = t >> 3, k = t & 7;
    float s = 0.f;
    for (int c = 0; c < 64; c++)
      for (int w = 0; w < 8; w++)
        s += part_w[((b*64 + c)*8 + w)*8 + k];
    femb[b][k] = s * (1.0f/64.0f);
  }
  __syncthreads();
  for (int idx = t; idx < 16*64; idx += 128){
    int b = idx >> 6, f = idx & 63;
    float s = fg_b1[f];
    for (int k = 0; k < 8; k++) s += femb[b][k] * fg_w1[f*8 + k];
    hid[b][f] = fmaxf(s, 0.f);
  }
  __syncthreads();
  if (t < 64){
    int b = t >> 2, e = t & 3;
    float s = 0.f;
    for (int c = 0; c < 64; c++) s += xmean[b*64 + c] * gate_w[e*64 + c];
    for (int f = 0; f < 64; f++) s += hid[b][f] * fg_w2[e*64 + f];
    lgt[b][e] = s + noise[b*4 + e] * 0.25f;   // NOISE_STD = 1/E
  }
  __syncthreads();
  if (t < 16){
    int b = t;
    float m = fmaxf(fmaxf(lgt[b][0], lgt[b][1]), fmaxf(lgt[b][2], lgt[b][3]));
    float p[4]; float sum = 0.f;
    for (int e = 0; e < 4; e++){ p[e] = expf(lgt[b][e] - m); sum += p[e]; }
    for (int e = 0; e < 4; e++) p[e] /= sum;
    int i1 = 0;
    for (int e = 1; e < 4; e++) if (p[e] > p[i1]) i1 = e;   // ties -> lowest idx (lax.top_k)
    int i2 = -1;
    for (int e = 0; e < 4; e++){ if (e == i1) continue; if (i2 < 0 || p[e] > p[i2]) i2 = e; }
    slot_e[b*2 + 0] = i1;
    slot_e[b*2 + 1] = i2;
    slot_g[b*2 + 0] = p[i1];
    slot_g[b*2 + 1] = p[i2];
    for (int e = 0; e < 4; e++) slot_of[b*4 + e] = (e == i1) ? 0 : ((e == i2) ? 1 : -1);
  }
}

// Both freq experts in one pass over X; weights via contiguous wave-uniform s_loads.
__global__ __launch_bounds__(256) void k_projfreq(const float2* __restrict__ X, const float* __restrict__ p0t,
    float2* __restrict__ Y, const int* __restrict__ slot_e,
    const float* __restrict__ hg_gain, const float* __restrict__ hg_decay,
    const float* __restrict__ lg_gain, const float* __restrict__ lg_decay){
  int b = blockIdx.z;
  int e0 = __builtin_amdgcn_readfirstlane(slot_e[b*2 + 0]);
  int e1 = __builtin_amdgcn_readfirstlane(slot_e[b*2 + 1]);
  bool f0 = (e0 == 0) || (e0 == 2);
  bool f1 = (e1 == 0) || (e1 == 2);
  if (!f0 && !f1) return;
  int j = blockIdx.y;
  int i0 = blockIdx.x * 64;
  int t = threadIdx.x;
  int lane = t & 63;
  int w = __builtin_amdgcn_readfirstlane(t >> 6);
  __shared__ float2 sx[64][64];
  for (int idx = t; idx < 4096; idx += 256){
    int c = idx >> 6, ii = idx & 63;
    sx[c][ii] = X[(((size_t)(b*64 + c))*65 + j)*128 + i0 + ii];
  }
  __syncthreads();
  int i = i0 + lane;
  const float* W0 = p0t + ((f0 ? (e0 >> 1) : (e1 >> 1)) * 2048) + w*8;
  const float* W1 = p0t + ((f1 ? (e1 >> 1) : (e0 >> 1)) * 2048) + w*8;
  float a0x[8] = {0,0,0,0,0,0,0,0}, a0y[8] = {0,0,0,0,0,0,0,0};
  float a1x[8] = {0,0,0,0,0,0,0,0}, a1y[8] = {0,0,0,0,0,0,0,0};
  for (int c = 0; c < 64; c++){
    float2 xv = sx[c][lane];
    const float* wc0 = W0 + c*32;
    const float* wc1 = W1 + c*32;
    #pragma unroll
    for (int k = 0; k < 8; k++){
      float w0v = wc0[k];
      a0x[k] += w0v * xv.x; a0y[k] += w0v * xv.y;
      float w1v = wc1[k];
      a1x[k] += w1v * xv.x; a1y[k] += w1v * xv.y;
    }
  }
  float fy = (float)(i < 64 ? i : i - 128) * (1.0f/128.0f);
  float fx = (float)j * (1.0f/128.0f);
  float fg = sqrtf(fy*fy + fx*fx);
  if (f0){
    float gain, decay, cmax;
    if (e0 == 0){ gain = *hg_gain; decay = *hg_decay; cmax = 3.0f; }
    else        { gain = *lg_gain; decay = *lg_decay; cmax = 1.0f; }
    float filt = (1.0f - expf(-gain*fg)) * expf(-decay*fg);
    filt = fminf(fmaxf(filt, 0.0f), cmax) * (1.0f/16384.0f);
    int bs = b*2 + 0;
    #pragma unroll
    for (int k = 0; k < 8; k++){
      int r = w*8 + k;
      Y[((size_t)(bs*32 + r))*8320 + j*128 + i] = make_float2(a0x[k]*filt, a0y[k]*filt);
    }
  }
  if (f1){
    float gain, decay, cmax;
    if (e1 == 0){ gain = *hg_gain; decay = *hg_decay; cmax = 3.0f; }
    else        { gain = *lg_gain; decay = *lg_decay; cmax = 1.0f; }
    float filt = (1.0f - expf(-gain*fg)) * expf(-decay*fg);
    filt = fminf(fmaxf(filt, 0.0f), cmax) * (1.0f/16384.0f);
    int bs = b*2 + 1;
    #pragma unroll
    for (int k = 0; k < 8; k++){
      int r = w*8 + k;
      Y[((size_t)(bs*32 + r))*8320 + j*128 + i] = make_float2(a1x[k]*filt, a1y[k]*filt);
    }
  }
}

// Merged: blocks [0,1024) = inverse 2-D FFT per (bs,r) for freq slots (512 thr);
//         blocks [1024,2048) = projA on MFMA, 256-px tile, conv slots only.
// Safe: X is dead (projfreq already complete); A overlays X.
__global__ __launch_bounds__(512) void k_ifta(float2* __restrict__ Y, const int* __restrict__ slot_e,
    const float* __restrict__ x, const float* __restrict__ proj0, float* __restrict__ A){
  __shared__ __align__(16) unsigned char ubuf[65536];
  int bid = blockIdx.x;
  int t = threadIdx.x;
  if (bid < 1024){
    // ---- ifft2 role ----
    int bs = bid >> 5, r = bid & 31;
    int es = slot_e[bs];
    if (es == 1 || es == 3) return;
    float2* z = (float2*)ubuf;
    int lane = t & 63, wv = t >> 6;
    if (t < 128){
      float s, c;
      sincosf(-6.283185307179586f * (float)t * (1.0f/128.0f), &s, &c);
      z[t] = make_float2(c, s);
    }
    __syncthreads();
    TwB T; init_twb(T, lane, (const float2*)z);
    __syncthreads();
    int rb = br6(lane);
    float2* Yb = Y + (size_t)(bs*32 + r) * 8320;

    for (int idx = t; idx < 8192; idx += 512){
      int j = idx >> 7, i = idx & 127;
      if (j == 0){
        float2 y0 = Yb[i];
        float2 y6 = Yb[8192 + i];
        z[pos7(i)] = make_float2(y0.x - y6.y, y0.y + y6.x);
      } else {
        z[(j << 7) | (pos7(i) ^ j)] = Yb[idx];
      }
    }
    __syncthreads();

    #pragma unroll
    for (int k = 0; k < 8; k++){
      int jj = wv*8 + k;
      float2 z0 = z[(jj << 7) | (pos7(lane) ^ jj)];
      float2 z1 = z[(jj << 7) | ((pos7(lane) + 32) ^ jj)];
      cpx a{z0.x, -z0.y}, b{z1.x, -z1.y};
      fft128(a, b, lane, T);
      int ia = (jj << 7) | (rb ^ jj);
      z[ia]      = make_float2(a.x, -a.y);
      z[ia | 64] = make_float2(b.x, -b.y);
    }
    __syncthreads();

    float* body = (float*)Yb;
    #pragma unroll 2
    for (int k = 0; k < 8; k++){
      int p = wv*8 + k;
      int h = 2*p, h1 = 2*p + 1;
      int ph = pos7(h), ph1 = pos7(h1);
      cpx a, b;
      if (lane == 0){
        float2 c0 = z[ph], c1 = z[ph1];
        a = { c0.x, c1.x };
        b = { c0.y, c1.y };
      } else {
        float2 yh = z[(lane << 7) | (ph ^ lane)];
        float2 y1 = z[(lane << 7) | (ph1 ^ lane)];
        a = { yh.x - y1.y, yh.y + y1.x };
        int lm = 64 - lane;
        float2 zh  = z[(lm << 7) | (ph ^ lm)];
        float2 z1_ = z[(lm << 7) | (ph1 ^ lm)];
        b = { zh.x + z1_.y, z1_.x - zh.y };
      }
      a.y = -a.y; b.y = -b.y;
      fft128(a, b, lane, T);
      int n0 = 2*rb;
      body[h*128 + n0]      = a.x;
      body[h1*128 + n0]     = -a.y;
      body[h*128 + n0 + 1]  = b.x;
      body[h1*128 + n0 + 1] = -b.y;
    }
  } else {
    // ---- projA role (512 thr, 256-px tile) ----
    int aid = bid - 1024;
    int b = aid >> 6;
    int e0 = __builtin_amdgcn_readfirstlane(slot_e[b*2 + 0]);
    int e1 = __builtin_amdgcn_readfirstlane(slot_e[b*2 + 1]);
    bool c0 = (e0 == 1) || (e0 == 3);
    bool c1 = (e1 == 1) || (e1 == 3);
    if (!c0 && !c1) return;
    unsigned short (*xs)[72] = (unsigned short(*)[72])ubuf;   // [256][72]
    int px0 = (aid & 63) * 256;
    int w = t >> 6, lane = t & 63;
    int h = lane & 15, g = lane >> 4;
    const float* xb = x + (size_t)b*64*16384;

    for (int idx = t; idx < 4096; idx += 512){
      int c = idx >> 6, pq = idx & 63;
      float4 v = *(const float4*)&xb[(size_t)c*16384 + px0 + pq*4];
      xs[pq*4 + 0][c] = (unsigned short)f2bf(v.x);
      xs[pq*4 + 1][c] = (unsigned short)f2bf(v.y);
      xs[pq*4 + 2][c] = (unsigned short)f2bf(v.z);
      xs[pq*4 + 3][c] = (unsigned short)f2bf(v.w);
    }

    bf16x8 af[2][2][2];
    #pragma unroll
    for (int s = 0; s < 2; s++){
      bool cv = (s == 0) ? c0 : c1;
      if (!cv) continue;
      int e = (s == 0) ? e0 : e1;
      const float* P0 = proj0 + e*2048;
      #pragma unroll
      for (int mr = 0; mr < 2; mr++)
        #pragma unroll
        for (int k0 = 0; k0 < 2; k0++){
          const float* p = P0 + (mr*16 + h)*64 + k0*32 + g*8;
          bf16x8 v;
          #pragma unroll
          for (int j = 0; j < 8; j++) v[j] = f2bf(p[j]);
          af[s][mr][k0] = v;
        }
    }
    __syncthreads();

    int pxw = w*32;
    #pragma unroll
    for (int nt = 0; nt < 2; nt++){
      int pxl = pxw + nt*16;
      int px  = px0 + pxl;
      bf16x8 bx[2];
      #pragma unroll
      for (int k0 = 0; k0 < 2; k0++)
        bx[k0] = *(bf16x8*)&xs[pxl + h][k0*32 + g*8];
      #pragma unroll
      for (int s = 0; s < 2; s++){
        bool cv = (s == 0) ? c0 : c1;
        if (!cv) continue;
        float* Ab = A + (size_t)((b*2 + s)*32)*16384;
        #pragma unroll
        for (int mr = 0; mr < 2; mr++){
          f32x4 acc = {0.f, 0.f, 0.f, 0.f};
          acc = __builtin_amdgcn_mfma_f32_16x16x32_bf16(af[s][mr][0], bx[0], acc, 0, 0, 0);
          acc = __builtin_amdgcn_mfma_f32_16x16x32_bf16(af[s][mr][1], bx[1], acc, 0, 0, 0);
          #pragma unroll
          for (int reg = 0; reg < 4; reg++){
            int r = mr*16 + g*4 + reg;
            Ab[(size_t)r*16384 + px + h] = acc[reg];
          }
        }
      }
    }
  }
}

// Merged conv experts: blockIdx.z==0 -> dw3->gelu->dw3; ==1 -> dw7->gelu->avgpool3.
__global__ __launch_bounds__(256) void k_conv(const float* __restrict__ A, float* __restrict__ bodyY,
    const float* __restrict__ w1g, const float* __restrict__ b1g,
    const float* __restrict__ w2g, const float* __restrict__ b2g,
    const float* __restrict__ wg, const float* __restrict__ bg,
    const int* __restrict__ slot_of){
  __shared__ __align__(16) float cbuf[5680];
  int by = blockIdx.y; int b = by >> 5, r = by & 31;
  int h0 = blockIdx.x * 16;
  int t = threadIdx.x;
  if (blockIdx.z == 0){
    int slot = slot_of[b*4 + 1];
    if (slot < 0) return;
    int bs = b*2 + slot;
    float* sin_ = cbuf;            // 20*130 = 2600
    float* st   = cbuf + 2600;     // 18*130 = 2340
    for (int i = t; i < 20*130; i += 256) sin_[i] = 0.f;
    for (int i = t; i < 18*130; i += 256) st[i] = 0.f;
    float w1[9], w2[9];
    #pragma unroll
    for (int k = 0; k < 9; k++){ w1[k] = w1g[r*9 + k]; w2[k] = w2g[r*9 + k]; }
    float b1 = b1g[r], b2 = b2g[r];
    __syncthreads();
    const float* ip = A + (size_t)(bs*32 + r)*16384;
    for (int idx = t; idx < 20*128; idx += 256){
      int li = idx >> 7, ww = idx & 127;
      int ih = h0 - 2 + li;
      if (ih >= 0 && ih < 128) sin_[li*130 + 1 + ww] = ip[ih*128 + ww];
    }
    __syncthreads();
    for (int idx = t; idx < 18*128; idx += 256){
      int li = idx >> 7, ww = idx & 127;
      int hs = h0 - 1 + li;
      if (hs >= 0 && hs < 128){
        float acc = b1;
        #pragma unroll
        for (int kh = 0; kh < 3; kh++)
          #pragma unroll
          for (int kw = 0; kw < 3; kw++)
            acc += w1[kh*3 + kw] * sin_[(li + kh)*130 + ww + kw];
        st[li*130 + 1 + ww] = gelu_exact(acc);
      }
    }
    __syncthreads();
    float* op = bodyY + (size_t)(bs*32 + r)*16640;
    for (int idx = t; idx < 16*128; idx += 256){
      int li = idx >> 7, ww = idx & 127;
      int ho = h0 + li;
      float acc = b2;
      #pragma unroll
      for (int kh = 0; kh < 3; kh++)
        #pragma unroll
        for (int kw = 0; kw < 3; kw++)
          acc += w2[kh*3 + kw] * st[(li + kh)*130 + ww + kw];
      op[ho*128 + ww] = acc;
    }
  } else {
    int slot = slot_of[b*4 + 3];
    if (slot < 0) return;
    int bs = b*2 + slot;
    float* sin_ = cbuf;            // 24*134 = 3216
    float* st   = cbuf + 3216;     // 18*134 = 2412
    float* wsh  = cbuf + 5628;     // 49
    for (int i = t; i < 24*134; i += 256) sin_[i] = 0.f;
    for (int i = t; i < 18*134; i += 256) st[i] = 0.f;
    if (t < 49) wsh[t] = wg[r*49 + t];
    float bias = bg[r];
    __syncthreads();
    const float* ip = A + (size_t)(bs*32 + r)*16384;
    for (int idx = t; idx < 24*128; idx += 256){
      int li = idx >> 7, ww = idx & 127;
      int ih = h0 - 4 + li;
      if (ih >= 0 && ih < 128) sin_[li*134 + 3 + ww] = ip[ih*128 + ww];
    }
    __syncthreads();
    for (int idx = t; idx < 18*128; idx += 256){
      int li = idx >> 7, ww = idx & 127;
      int hs = h0 - 1 + li;
      if (hs >= 0 && hs < 128){
        float acc = bias;
        #pragma unroll
        for (int kh = 0; kh < 7; kh++)
          #pragma unroll
          for (int kw = 0; kw < 7; kw++)
            acc += wsh[kh*7 + kw] * sin_[(li + kh)*134 + ww + kw];
        st[li*134 + 1 + ww] = gelu_exact(acc);
      }
    }
    __syncthreads();
    float* op = bodyY + (size_t)(bs*32 + r)*16640;
    for (int idx = t; idx < 16*128; idx += 256){
      int li = idx >> 7, ww = idx & 127;
      int ho = h0 + li;
      float acc = 0.f;
      #pragma unroll
      for (int kh = 0; kh < 3; kh++)
        #pragma unroll
        for (int kw = 0; kw < 3; kw++)
          acc += st[(li + kh)*134 + ww + kw];
      op[ho*128 + ww] = acc * (1.0f/9.0f);
    }
  }
}

// Final combine on MFMA, 2-pass epilogue (as r15).
__global__ __launch_bounds__(256) void k_combine(const float* __restrict__ x, const float* __restrict__ bodyY,
    const float* __restrict__ proj1, const float* __restrict__ proj2,
    const int* __restrict__ slot_e, const float* __restrict__ slot_g,
    float* __restrict__ out){
  __shared__ __align__(16) unsigned char smem[57344];
  unsigned short (*xs)[72]            = (unsigned short(*)[72])(smem);
  unsigned short (*bs2)[128][36]      = (unsigned short(*)[128][36])(smem + 18432);
  unsigned short (*sblk)[4][2][16][40] = (unsigned short(*)[4][2][16][40])(smem + 36864);
  float* obuf = (float*)smem;

  int b = blockIdx.y;
  int px0 = blockIdx.x * 128;
  int t = threadIdx.x;
  int w = t >> 6, lane = t & 63;
  int h = lane & 15, g = lane >> 4;
  int ea = __builtin_amdgcn_readfirstlane(slot_e[b*2 + 0]);
  int eb = __builtin_amdgcn_readfirstlane(slot_e[b*2 + 1]);
  float ga = slot_g[b*2 + 0], gb = slot_g[b*2 + 1];
  float gs = ga + gb;

  const float* xb = x + (size_t)b*64*16384;
  float* ob = out + (size_t)b*64*16384;
  const float* Bd0 = bodyY + (size_t)(b*2 + 0)*32*16640;
  const float* Bd1 = bodyY + (size_t)(b*2 + 1)*32*16640;

  for (int idx = t; idx < 2048; idx += 256){
    int c = idx >> 5, pq = idx & 31;
    float4 v = *(const float4*)&xb[(size_t)c*16384 + px0 + pq*4];
    xs[pq*4 + 0][c] = (unsigned short)f2bf(v.x);
    xs[pq*4 + 1][c] = (unsigned short)f2bf(v.y);
    xs[pq*4 + 2][c] = (unsigned short)f2bf(v.z);
    xs[pq*4 + 3][c] = (unsigned short)f2bf(v.w);
  }
  for (int idx = t; idx < 2048; idx += 256){
    int s = idx >> 10, r = (idx >> 5) & 31, pq = idx & 31;
    const float* Bod = (s == 0) ? Bd0 : Bd1;
    float4 v = *(const float4*)&Bod[(size_t)r*16640 + px0 + pq*4];
    bs2[s][pq*4 + 0][r] = (unsigned short)f2bf(v.x);
    bs2[s][pq*4 + 1][r] = (unsigned short)f2bf(v.y);
    bs2[s][pq*4 + 2][r] = (unsigned short)f2bf(v.z);
    bs2[s][pq*4 + 3][r] = (unsigned short)f2bf(v.w);
  }

  bf16x8 a1[2][2][2];
  #pragma unroll
  for (int s = 0; s < 2; s++){
    const float* P1 = proj1 + (s == 0 ? ea : eb)*2048;
    #pragma unroll
    for (int mr = 0; mr < 2; mr++)
      #pragma unroll
      for (int k0 = 0; k0 < 2; k0++){
        const float* p = P1 + (mr*16 + h)*64 + k0*32 + g*8;
        bf16x8 v;
        #pragma unroll
        for (int j = 0; j < 8; j++) v[j] = f2bf(p[j]);
        a1[s][mr][k0] = v;
      }
  }
  bf16x8 a2[2][4];
  #pragma unroll
  for (int s = 0; s < 2; s++){
    const float* P2 = proj2 + (s == 0 ? ea : eb)*2048;
    #pragma unroll
    for (int mc = 0; mc < 4; mc++){
      const float* p = P2 + (mc*16 + h)*32 + g*8;
      bf16x8 v;
      #pragma unroll
      for (int j = 0; j < 8; j++) v[j] = f2bf(p[j]);
      a2[s][mc] = v;
    }
  }
  __syncthreads();

  int pxw = w*32;
  #pragma unroll
  for (int nt = 0; nt < 2; nt++){
    int pxl = pxw + nt*16;
    bf16x8 bx[2];
    #pragma unroll
    for (int k0 = 0; k0 < 2; k0++)
      bx[k0] = *(bf16x8*)&xs[pxl + h][k0*32 + g*8];
    f32x4 acc1[2][2];
    #pragma unroll
    for (int s = 0; s < 2; s++)
      #pragma unroll
      for (int mr = 0; mr < 2; mr++){
        f32x4 acc = {0.f, 0.f, 0.f, 0.f};
        acc = __builtin_amdgcn_mfma_f32_16x16x32_bf16(a1[s][mr][0], bx[0], acc, 0, 0, 0);
        acc = __builtin_amdgcn_mfma_f32_16x16x32_bf16(a1[s][mr][1], bx[1], acc, 0, 0, 0);
        acc1[s][mr] = acc;
      }
    #pragma unroll
    for (int s = 0; s < 2; s++){
      float gw = (s == 0) ? ga : gb;
      #pragma unroll
      for (int mr = 0; mr < 2; mr++){
        int r0 = mr*16 + g*4;
        unsigned short b4[4];
        *(uint2*)b4 = *(uint2*)&bs2[s][pxl + h][r0];
        unsigned pk0, pk1;
        {
          float bv0 = __uint_as_float(((unsigned)b4[0]) << 16);
          float bv1 = __uint_as_float(((unsigned)b4[1]) << 16);
          float bv2 = __uint_as_float(((unsigned)b4[2]) << 16);
          float bv3 = __uint_as_float(((unsigned)b4[3]) << 16);
          float s0 = gw * bv0 * silu(acc1[s][mr][0]);
          float s1 = gw * bv1 * silu(acc1[s][mr][1]);
          float s2 = gw * bv2 * silu(acc1[s][mr][2]);
          float s3 = gw * bv3 * silu(acc1[s][mr][3]);
          pk0 = (unsigned)(unsigned short)f2bf(s0) | ((unsigned)(unsigned short)f2bf(s1) << 16);
          pk1 = (unsigned)(unsigned short)f2bf(s2) | ((unsigned)(unsigned short)f2bf(s3) << 16);
        }
        uint2 pv; pv.x = pk0; pv.y = pk1;
        *(uint2*)&sblk[nt][w][s][h][r0] = pv;
      }
    }
  }
  __syncthreads();

  #pragma unroll
  for (int nt = 0; nt < 2; nt++){
    bf16x8 sb0 = *(bf16x8*)&sblk[nt][w][0][h][g*8];
    bf16x8 sb1 = *(bf16x8*)&sblk[nt][w][1][h][g*8];
    #pragma unroll
    for (int mc = 0; mc < 4; mc++){
      f32x4 acc = {0.f, 0.f, 0.f, 0.f};
      acc = __builtin_amdgcn_mfma_f32_16x16x32_bf16(a2[0][mc], sb0, acc, 0, 0, 0);
      acc = __builtin_amdgcn_mfma_f32_16x16x32_bf16(a2[1][mc], sb1, acc, 0, 0, 0);
      #pragma unroll
      for (int reg = 0; reg < 4; reg++){
        int c = mc*16 + g*4 + reg;
        obuf[(w*64 + c)*36 + nt*16 + h] = acc[reg];
      }
    }
  }
  int fq = lane & 7, cr = lane >> 3;
  const float* xw = xb + px0 + w*32;
  float* ow = ob + px0 + w*32;
  #pragma unroll
  for (int i = 0; i < 8; i++){
    int c = i*8 + cr;
    float4 v = *(float4*)&obuf[(w*64 + c)*36 + fq*4];
    float4 xv4 = *(const float4*)&xw[(size_t)c*16384 + fq*4];
    *(float4*)&ow[(size_t)c*16384 + fq*4] =
      make_float4(gs*xv4.x + v.x, gs*xv4.y + v.y, gs*xv4.z + v.z, gs*xv4.w + v.w);
  }
}

} // namespace

extern "C" void kernel_launch(void* const* d_in, const int* in_sizes, int n_in,
                              void* d_out, int out_size, void* d_ws, size_t ws_size,
                              hipStream_t stream) {
  (void)in_sizes; (void)n_in; (void)out_size; (void)ws_size;
  const float* x        = (const float*)d_in[0];
  const float* noise    = (const float*)d_in[1];
  const float* gate_w   = (const float*)d_in[2];
  const float* fg_w1    = (const float*)d_in[3];
  const float* fg_b1    = (const float*)d_in[4];
  const float* fg_w2    = (const float*)d_in[5];
  const float* proj0    = (const float*)d_in[6];
  const float* proj1    = (const float*)d_in[7];
  const float* proj2    = (const float*)d_in[8];
  const float* hg_gain  = (const float*)d_in[9];
  const float* hg_decay = (const float*)d_in[10];
  const float* hf_w1    = (const float*)d_in[11];
  const float* hf_b1    = (const float*)d_in[12];
  const float* hf_w2    = (const float*)d_in[13];
  const float* hf_b2    = (const float*)d_in[14];
  const float* lg_gain  = (const float*)d_in[15];
  const float* lg_decay = (const float*)d_in[16];
  const float* lf_w     = (const float*)d_in[17];
  const float* lf_b     = (const float*)d_in[18];
  float* out = (float*)d_out;

  // ws (floats):
  //  [0, 17039360)            X spectra [1024][65][128] f2 ; later overlaid by A [32 bs][32 r][16384]
  //  [17039360, 34078720)     Yspec/body [32 bs][32 r][65*128 f2]
  //  tail: xmean 1024 | part_w 65536 | p0t 4096 | slot_g 32 | slot_e 32 (int) | slot_of 64 (int)
  float* ws = (float*)d_ws;
  float2* X  = (float2*)ws;
  float*  A  = ws;
  float*  Yf = ws + 17039360;
  float2* Y2 = (float2*)Yf;
  float*  tail   = ws + 34078720;
  float*  xmean  = tail;
  float*  part_w = xmean + 1024;
  float*  p0t    = part_w + 65536;
  float*  slot_g = p0t + 4096;
  int*    slot_e = (int*)(slot_g + 32);
  int*    slot_of = slot_e + 32;

  // 1) forward FFT + energy (twiddles built in-LDS)
  k_fft2fwd<<<1024, 512, 0, stream>>>(x, X, part_w, xmean);
  // 2) routing + p0t transpose
  k_routing<<<1, 128, 0, stream>>>(xmean, part_w, noise, gate_w, fg_w1, fg_b1, fg_w2,
                                   proj0, p0t, slot_e, slot_of, slot_g);
  // 3) frequency-domain projections (X alive)
  k_projfreq<<<dim3(2,65,16), 256, 0, stream>>>(X, p0t, Y2, slot_e,
                                                hg_gain, hg_decay, lg_gain, lg_decay);
  // 4) merged inverse FFTs + projA (X dead; A overlays X)
  k_ifta<<<2048, 512, 0, stream>>>(Y2, slot_e, x, proj0, A);
  // 5) merged conv experts
  k_conv<<<dim3(8,512,2), 256, 0, stream>>>(A, Yf, hf_w1, hf_b1, hf_w2, hf_b2,
                                            lf_w, lf_b, slot_of);
  // 6) final combine
  k_combine<<<dim3(128,16), 256, 0, stream>>>(x, Yf, proj1, proj2, slot_e, slot_g, out);
}